// Round 4
// baseline (675.983 us; speedup 1.0000x reference)
//
#include <hip/hip_runtime.h>

// Problem constants (reference: N=65536, D=512, S=262144)
#define NROWS 65536
#define DCOLS 512
#define D4    128   // float4 per row
#define CHUNK 256   // rows per chunk (= threads per block in scan kernel)
#define NCHUNK (NROWS / CHUNK)  // 256 blocks

typedef float f32x4 __attribute__((ext_vector_type(4)));

// ---------------------------------------------------------------------------
// Workspace layout (ints):
//   [0]            total
//   [64 .. ]       idx16[S]  (unsigned short, 512 KB), 256-byte aligned
// ---------------------------------------------------------------------------

// K1: fused scan + idx build. ONE kernel, no inter-block communication, no
// workspace-init requirement (ws is poisoned every iteration, so lookback /
// atomic-flag schemes would need an extra memset dispatch).
//
// Block b computes its exclusive offset by REDUNDANTLY summing
// rep[0 .. b*256): rep is 256 KB -> L2/L3-hot, total redundant reads across
// all blocks ~34 MB of L2 traffic (~1 us). Then it Hillis-Steele-scans its
// own 256-row chunk in LDS and writes its ushort idx spans (~458 KB total).
// Replaces the previous 3-kernel chain (chunk_sum -> scan_chunks ->
// build_idx): 2 fewer launches, no serial dependency on two tiny kernels.
__global__ __launch_bounds__(256) void scan_idx_kernel(const int* __restrict__ rep,
                                                       unsigned short* __restrict__ idx16,
                                                       int* __restrict__ totalp,
                                                       int S) {
    const int b = blockIdx.x;
    const int t = threadIdx.x;

    // ---- exclusive chunk offset: sum of rep[0 .. b*CHUNK), coalesced ----
    int part = 0;
    for (int k = t; k < b * CHUNK; k += CHUNK) part += rep[k];
#pragma unroll
    for (int off = 32; off; off >>= 1) part += __shfl_down(part, off);
    __shared__ int wsum[4];
    if ((t & 63) == 0) wsum[t >> 6] = part;
    __syncthreads();
    const int ex = wsum[0] + wsum[1] + wsum[2] + wsum[3];

    // ---- inclusive scan of own 256-row chunk ----
    const int i = b * CHUNK + t;
    const int r = rep[i];
    __shared__ int s[CHUNK];
    s[t] = r;
    __syncthreads();
    for (int off = 1; off < CHUNK; off <<= 1) {
        int add = (t >= off) ? s[t - off] : 0;
        __syncthreads();
        s[t] += add;
        __syncthreads();
    }
    int end = ex + s[t];
    if (i == NROWS - 1) totalp[0] = end;

    const int start = end - r;
    if (start >= S) return;
    if (end > S) end = S;
    for (int j = start; j < end; ++j) idx16[j] = (unsigned short)i;
}

// ---------------------------------------------------------------------------
// K2: gather — byte-identical structure to round 3 (single-variable rigor).
// One wave per FOUR output rows; batch all 8 row-loads then all 8 row-stores
// (8 KB same-direction bursts). Bijective XCD swizzle keeps adjacent output
// rows (which share a source row ~3.5x) on the same XCD's L2. Plain stores
// (nt measured slower in round 1->2).
// ---------------------------------------------------------------------------
__global__ __launch_bounds__(256) void gather_kernel(const f32x4* __restrict__ feeds,
                                                     const unsigned short* __restrict__ idx16,
                                                     const int* __restrict__ totalp,
                                                     f32x4* __restrict__ out,
                                                     int S) {
    // Bijective XCD swizzle: grid = S/16 = 16384 blocks, divisible by 8.
    int bid = blockIdx.x;
    const int cpx = gridDim.x >> 3;
    bid = (bid & 7) * cpx + (bid >> 3);

    const int wave = bid * 4 + (threadIdx.x >> 6);
    const int lane = threadIdx.x & 63;
    const int j0 = wave * 4;              // first of 4 output rows
    if (j0 >= S) return;

    const int total = totalp[0];

    f32x4 a[4], b[4];
#pragma unroll
    for (int q = 0; q < 4; ++q) {
        const int j = j0 + q;
        if (j < total) {
            const int si = idx16[j];
            const f32x4* src = feeds + (unsigned)(si * D4);
            a[q] = src[lane];
            b[q] = src[lane + 64];
        } else {
            a[q] = (f32x4)0.f;
            b[q] = (f32x4)0.f;
        }
    }
#pragma unroll
    for (int q = 0; q < 4; ++q) {
        f32x4* dst = out + (long long)(j0 + q) * D4;
        dst[lane]      = a[q];
        dst[lane + 64] = b[q];
    }
}

extern "C" void kernel_launch(void* const* d_in, const int* in_sizes, int n_in,
                              void* d_out, int out_size, void* d_ws, size_t ws_size,
                              hipStream_t stream) {
    const float* feeds = (const float*)d_in[0];
    const int*   rep   = (const int*)d_in[1];
    const int S = out_size / DCOLS;

    int* ws     = (int*)d_ws;
    int* totalp = ws;                                   // 1 int
    unsigned short* idx16 = (unsigned short*)(ws + 64); // S ushorts = 512 KB

    scan_idx_kernel<<<NCHUNK, CHUNK, 0, stream>>>(rep, idx16, totalp, S);
    // 16 output rows per block (4 waves x 4 rows) -> S/16 = 16384 blocks.
    gather_kernel<<<S / 16, 256, 0, stream>>>((const f32x4*)feeds, idx16, totalp,
                                              (f32x4*)d_out, S);
}

// Round 5
// 592.336 us; speedup vs baseline: 1.1412x; 1.1412x over previous
//
#include <hip/hip_runtime.h>

// Problem constants (reference: N=65536, D=512, S=262144)
#define NROWS 65536
#define DCOLS 512
#define D4    128   // float4 per row
#define CHUNK 256   // rows per chunk
#define NCHUNK (NROWS / CHUNK)  // 256 chunks

typedef float f32x4 __attribute__((ext_vector_type(4)));

// ---------------------------------------------------------------------------
// Workspace layout (ints):
//   [0   .. 255]  chunksum[256]
//   [256 .. 511]  chunkoff[256]  (exclusive prefix of chunksum)
//   [512]         total
//   [768 .. ]     idx[S] (int, 1 MiB)
// ---------------------------------------------------------------------------

// K1: per-chunk sums of rep. 256 blocks x 256 threads. (measured fine in r3)
__global__ __launch_bounds__(256) void chunk_sum_kernel(const int* __restrict__ rep,
                                                        int* __restrict__ chunksum) {
    const int b = blockIdx.x;
    const int t = threadIdx.x;
    int v = rep[b * CHUNK + t];
#pragma unroll
    for (int off = 32; off; off >>= 1) v += __shfl_down(v, off);
    __shared__ int ws4[4];
    if ((t & 63) == 0) ws4[t >> 6] = v;
    __syncthreads();
    if (t == 0) chunksum[b] = ws4[0] + ws4[1] + ws4[2] + ws4[3];
}

// K2: exclusive scan of 256 chunk sums + total. One tiny block. (r3)
__global__ __launch_bounds__(256) void scan_chunks_kernel(const int* __restrict__ chunksum,
                                                          int* __restrict__ chunkoff,
                                                          int* __restrict__ totalp) {
    __shared__ int s[NCHUNK];
    const int t = threadIdx.x;
    const int v = chunksum[t];
    s[t] = v;
    __syncthreads();
    for (int off = 1; off < NCHUNK; off <<= 1) {
        int add = (t >= off) ? s[t - off] : 0;
        __syncthreads();
        s[t] += add;
        __syncthreads();
    }
    chunkoff[t] = s[t] - v;            // exclusive prefix
    if (t == NCHUNK - 1) totalp[0] = s[t];
}

// K3: per-chunk LDS scan + write int idx spans. 256 blocks x 256 threads.
// (r3 structure, int output to keep the gather byte-identical to round 0.)
__global__ __launch_bounds__(256) void build_idx_kernel(const int* __restrict__ rep,
                                                        const int* __restrict__ chunkoff,
                                                        int* __restrict__ idx,
                                                        int S) {
    const int b = blockIdx.x;
    const int t = threadIdx.x;
    const int i = b * CHUNK + t;
    const int r = rep[i];
    __shared__ int s[CHUNK];
    s[t] = r;
    __syncthreads();
    for (int off = 1; off < CHUNK; off <<= 1) {
        int add = (t >= off) ? s[t - off] : 0;
        __syncthreads();
        s[t] += add;
        __syncthreads();
    }
    int end = chunkoff[b] + s[t];
    const int start = end - r;
    if (start >= S) return;
    if (end > S) end = S;
    for (int j = start; j < end; ++j) idx[j] = i;
}

// ---------------------------------------------------------------------------
// K4: gather — ROUND-0 STRUCTURE RESTORED (best measured: 609 us).
// One wave per output row; nontemporal stores. In this output-centric form
// feeds is re-read ~3.5x through L3, so nt on the 512 MiB output stream
// protects that reuse (nt won here in r0 vs r3's plain: 609 vs 620, while
// losing in the no-reuse expand structure r1->r2: 640 vs 630).
// ---------------------------------------------------------------------------
__global__ __launch_bounds__(256) void gather_kernel(const f32x4* __restrict__ feeds,
                                                     const int* __restrict__ idx,
                                                     const int* __restrict__ totalp,
                                                     f32x4* __restrict__ out,
                                                     int S) {
    const int wave = (int)((blockIdx.x * blockDim.x + threadIdx.x) >> 6);
    const int lane = threadIdx.x & 63;
    if (wave >= S) return;

    const int total = totalp[0];

    f32x4 a = (f32x4)0.f;
    f32x4 b = (f32x4)0.f;
    if (wave < total) {
        const int si = idx[wave];
        const f32x4* src = feeds + (long long)si * D4;
        a = src[lane];
        b = src[lane + 64];
    }
    f32x4* dst = out + (long long)wave * D4;
    __builtin_nontemporal_store(a, dst + lane);
    __builtin_nontemporal_store(b, dst + lane + 64);
}

extern "C" void kernel_launch(void* const* d_in, const int* in_sizes, int n_in,
                              void* d_out, int out_size, void* d_ws, size_t ws_size,
                              hipStream_t stream) {
    const float* feeds = (const float*)d_in[0];
    const int*   rep   = (const int*)d_in[1];
    const int S = out_size / DCOLS;

    int* ws       = (int*)d_ws;
    int* chunksum = ws;            // 256 ints
    int* chunkoff = ws + 256;      // 256 ints
    int* totalp   = ws + 512;      // 1 int
    int* idx      = ws + 768;      // S ints = 1 MiB

    chunk_sum_kernel<<<NCHUNK, CHUNK, 0, stream>>>(rep, chunksum);
    scan_chunks_kernel<<<1, NCHUNK, 0, stream>>>(chunksum, chunkoff, totalp);
    build_idx_kernel<<<NCHUNK, CHUNK, 0, stream>>>(rep, chunkoff, idx, S);
    // One wave per output row: S waves -> S*64 threads / 256 = S/4 blocks.
    gather_kernel<<<S / 4, 256, 0, stream>>>((const f32x4*)feeds, idx, totalp,
                                             (f32x4*)d_out, S);
}